// Round 5
// baseline (685.302 us; speedup 1.0000x reference)
//
#include <hip/hip_runtime.h>
#include <stdint.h>

// ---------------------------------------------------------------------------
// LayerNormDenseGeneral: y = LN(x)*scale+bias; z = y @ W.  Outputs (z, y).
// Shapes: x[S,B,H]=[2048,4,2048] fp32, W[H,F]=[2048,8192] fp32.
// Round 7: GEMM software-pipelined at TILE granularity with register
// fragment double-buffering. Round-6 post-mortem: per-K-tile timeline was
// LDS(96 ds_read_b128 ~1150cyc) THEN MFMA(1030cyc) -- serially dependent
// within a tile, so pipes alternated (2800 cyc/tile == measured 300us,
// MfmaUtil 37% == 1030/2800). Body t now does: stage(t+3); ds_read frags(t)
// -> reg set (t&1); MFMA(t-1) on reg set ((t-1)&1)  [no dependence on this
// body's reads -> matrix pipe runs concurrently with LDS unit];
// vmcnt(8) lgkmcnt(0); barrier. Ledger unchanged from r6 (never drains;
// stages overwrite only buffers whose reads drained a barrier ago).
// LN + transpose kernels byte-identical for counter isolation.
// ws layout: [0, M*K*2) = A bf16 ; [M*K*2, M*K*2 + F*K*2) = Bt bf16. 64 MiB.
// ---------------------------------------------------------------------------

typedef __attribute__((ext_vector_type(8))) short short8;   // 8 x bf16 bits
typedef __attribute__((ext_vector_type(4))) float floatx4;  // MFMA acc

__device__ __forceinline__ unsigned short f2bf(float f) {
    unsigned u = __builtin_bit_cast(unsigned, f);
    u += 0x7fffu + ((u >> 16) & 1u);   // round-to-nearest-even
    return (unsigned short)(u >> 16);
}

// ---------------- LayerNorm: one block per row, H=2048 ---------------------
__global__ __launch_bounds__(256) void ln_kernel(
    const float* __restrict__ x, const float* __restrict__ scale,
    const float* __restrict__ bias, float* __restrict__ y,
    unsigned short* __restrict__ ybf, int H)
{
    const int row = blockIdx.x;
    const float* xr = x + (size_t)row * H;
    const int tid = threadIdx.x;

    // H = 2048: each thread handles float4 at [tid] and [tid+256]
    float4 v0 = ((const float4*)xr)[tid];
    float4 v1 = ((const float4*)xr)[tid + 256];

    float s  = v0.x + v0.y + v0.z + v0.w + v1.x + v1.y + v1.z + v1.w;
    float ss = v0.x*v0.x + v0.y*v0.y + v0.z*v0.z + v0.w*v0.w
             + v1.x*v1.x + v1.y*v1.y + v1.z*v1.z + v1.w*v1.w;

    // wave(64) reduce
    #pragma unroll
    for (int off = 32; off > 0; off >>= 1) {
        s  += __shfl_down(s,  off, 64);
        ss += __shfl_down(ss, off, 64);
    }
    __shared__ float rs[4], rq[4];
    if ((tid & 63) == 0) { rs[tid >> 6] = s; rq[tid >> 6] = ss; }
    __syncthreads();
    float ts = rs[0] + rs[1] + rs[2] + rs[3];
    float tq = rq[0] + rq[1] + rq[2] + rq[3];
    float mean = ts / (float)H;
    float var  = tq / (float)H - mean * mean;
    float rstd = rsqrtf(var + 1e-6f);

    float4 sc0 = ((const float4*)scale)[tid];
    float4 sc1 = ((const float4*)scale)[tid + 256];
    float4 b0  = ((const float4*)bias)[tid];
    float4 b1  = ((const float4*)bias)[tid + 256];

    float4 o0, o1;
    o0.x = (v0.x - mean) * rstd * sc0.x + b0.x;
    o0.y = (v0.y - mean) * rstd * sc0.y + b0.y;
    o0.z = (v0.z - mean) * rstd * sc0.z + b0.z;
    o0.w = (v0.w - mean) * rstd * sc0.w + b0.w;
    o1.x = (v1.x - mean) * rstd * sc1.x + b1.x;
    o1.y = (v1.y - mean) * rstd * sc1.y + b1.y;
    o1.z = (v1.z - mean) * rstd * sc1.z + b1.z;
    o1.w = (v1.w - mean) * rstd * sc1.w + b1.w;

    float* yr = y + (size_t)row * H;
    ((float4*)yr)[tid]       = o0;
    ((float4*)yr)[tid + 256] = o1;

    unsigned short* br = ybf + (size_t)row * H;
    uint2 p0, p1;
    p0.x = (unsigned)f2bf(o0.x) | ((unsigned)f2bf(o0.y) << 16);
    p0.y = (unsigned)f2bf(o0.z) | ((unsigned)f2bf(o0.w) << 16);
    p1.x = (unsigned)f2bf(o1.x) | ((unsigned)f2bf(o1.y) << 16);
    p1.y = (unsigned)f2bf(o1.z) | ((unsigned)f2bf(o1.w) << 16);
    ((uint2*)br)[tid]       = p0;
    ((uint2*)br)[tid + 256] = p1;
}

// -------- transpose-cast: W[K][F] fp32 -> Bt[F][K] bf16, 64x64 tiles -------
__global__ __launch_bounds__(256) void transpose_cast_kernel(
    const float* __restrict__ W, unsigned short* __restrict__ Bt,
    int K, int F)
{
    __shared__ float tile[64][65];
    const int kBase = blockIdx.y * 64;
    const int fBase = blockIdx.x * 64;
    const int tid = threadIdx.x;

    // read: 4 passes x (16 rows of 64 floats), coalesced float4
    #pragma unroll
    for (int p = 0; p < 4; ++p) {
        int kl = (tid >> 4) + p * 16;
        int fl = (tid & 15) * 4;
        float4 v = *(const float4*)&W[(size_t)(kBase + kl) * F + fBase + fl];
        tile[kl][fl]     = v.x;
        tile[kl][fl + 1] = v.y;
        tile[kl][fl + 2] = v.z;
        tile[kl][fl + 3] = v.w;
    }
    __syncthreads();

    // write: 2 passes x (32 f-rows), each thread packs 8 bf16 = 16B store
    #pragma unroll
    for (int p = 0; p < 2; ++p) {
        int fl = (tid >> 3) + p * 32;
        int k8 = (tid & 7) * 8;
        unsigned w[4];
        #pragma unroll
        for (int j = 0; j < 4; ++j) {
            unsigned lo = f2bf(tile[k8 + 2*j][fl]);
            unsigned hi = f2bf(tile[k8 + 2*j + 1][fl]);
            w[j] = lo | (hi << 16);
        }
        uint4 out = make_uint4(w[0], w[1], w[2], w[3]);
        *(uint4*)&Bt[(size_t)(fBase + fl) * K + kBase + k8] = out;
    }
}

// ---------------- GEMM: C[M][N] = A[M][K] * Bt[N][K]^T (bf16 -> fp32) ------
// 256x256 tile, BK=32, 512 threads = 8 waves (2M x 4N), wave tile 128x64.
// LDS ring: 4 bufs x (A[256][32] @ 0 + B[256][32] @ 8192 shorts) = 128 KiB.
// Row = 64B = 4 chunks of 16B; phys slot s of row r holds logical chunk
// s ^ ((r>>1)&3) -> ds_read_b128 conflict-free (r5/r6: counter = 0).
// gload_lds dest linear; inverse XOR on the per-lane global source address.
//
// Pipeline (register fragment double-buffer, sets X/Y by tile parity):
//   body t: stage(t+3 clamped) -> buf[(t+3)&3]
//           ds_read 12 frags(t) from buf[t&3] -> set (t&1)
//           if (t>0) 32 MFMA on set ((t-1)&1)    [independent of the reads]
//           s_waitcnt vmcnt(8) lgkmcnt(0); s_barrier
//   epilogue: 32 MFMA on set ((NT-1)&1)
// vmcnt(8) retires tile t+1's 4 loads (t+2,t+3's 8 stay in flight -> never
// drains). lgkmcnt(0) drains this wave's reads of buf[t&3] before the
// barrier so body t+1's stages may overwrite buf[t&3]... (they target
// buf[(t+4)&3]=buf[t&3]). MFMA(t-1) consumes registers only; its source
// buffer buf[(t-1)&3] is overwritten by stages in body t -- reads of it
// drained at barrier t-1. Requires NT % 4 == 0 (K % 128 == 0).
#define GBM 256
#define GBN 256
#define GBK 32

__device__ __forceinline__ void gload16(const unsigned short* src,
                                        unsigned short* dst) {
    __builtin_amdgcn_global_load_lds(
        (const __attribute__((address_space(1))) unsigned int*)src,
        (__attribute__((address_space(3))) unsigned int*)dst, 16, 0, 0);
}

// stage one operand K-tile (256 rows x 32 k = 16KB) = 2 loads/thread
__device__ __forceinline__ void stage_op(
    const unsigned short* __restrict__ g, unsigned short* dst,
    int t, int K, int tid)
{
    #pragma unroll
    for (int i = 0; i < 2; ++i) {
        int e = i * 512 + tid;
        int r = e >> 2;                         // row 0..255
        int c = (e & 3) ^ ((r >> 1) & 3);       // inverse swizzle on source
        gload16(g + (size_t)r * K + t * GBK + c * 8, dst + e * 8);
    }
}

__device__ __forceinline__ void read_frags(
    const unsigned short* bufA, const unsigned short* bufB,
    int rowA0, int rowB0, int soff,
    short8 (&a0)[4], short8 (&a1)[4], short8 (&b)[4])
{
    #pragma unroll
    for (int i = 0; i < 4; ++i)
        a0[i] = *(const short8*)(bufA + (rowA0 + i * 16) * 32 + soff);
    #pragma unroll
    for (int j = 0; j < 4; ++j)
        b[j] = *(const short8*)(bufB + (rowB0 + j * 16) * 32 + soff);
    #pragma unroll
    for (int i = 0; i < 4; ++i)
        a1[i] = *(const short8*)(bufA + (rowA0 + 64 + i * 16) * 32 + soff);
}

__device__ __forceinline__ void mfma_tile(
    const short8 (&a0)[4], const short8 (&a1)[4], const short8 (&b)[4],
    floatx4 (&acc)[8][4])
{
    __builtin_amdgcn_s_setprio(1);
    #pragma unroll
    for (int i = 0; i < 4; ++i)
        #pragma unroll
        for (int j = 0; j < 4; ++j)
            acc[i][j] = __builtin_amdgcn_mfma_f32_16x16x32_bf16(
                a0[i], b[j], acc[i][j], 0, 0, 0);
    #pragma unroll
    for (int i = 0; i < 4; ++i)
        #pragma unroll
        for (int j = 0; j < 4; ++j)
            acc[4 + i][j] = __builtin_amdgcn_mfma_f32_16x16x32_bf16(
                a1[i], b[j], acc[4 + i][j], 0, 0, 0);
    __builtin_amdgcn_s_setprio(0);
}

__global__ __launch_bounds__(512, 2) void gemm_bf16_8w(
    const unsigned short* __restrict__ A,   // [M][K] bf16
    const unsigned short* __restrict__ Bt,  // [N][K] bf16
    float* __restrict__ C,                  // [M][N] fp32
    int M, int N, int K)
{
    __shared__ __align__(128) unsigned short lds[4][16384]; // 128 KiB ring

    const int tid   = threadIdx.x;
    const int lane  = tid & 63;
    const int wave  = tid >> 6;     // 0..7
    const int waveM = wave >> 2;    // 0..1
    const int waveN = wave & 3;     // 0..3
    const int quad  = lane >> 4;    // 0..3 (k-chunk)
    const int l16   = lane & 15;
    // fragment rows are (multiple of 16) + l16, so (r>>1)&3 == (l16>>1)&3:
    const int soff  = (quad ^ ((l16 >> 1) & 3)) * 8;  // swizzled slot (shorts)
    const int rowA0 = waveM * 128 + l16;
    const int rowB0 = waveN * 64 + l16;

    // XCD-aware bijective swizzle (nwg = 1024, divisible by 8)
    const int nwg = gridDim.x;
    const int cpx = nwg >> 3;
    const int bid = blockIdx.x;
    const int wg  = (bid & 7) * cpx + (bid >> 3);
    const int tilesN = N >> 8;
    const int tm = wg / tilesN;
    const int tn = wg % tilesN;

    const unsigned short* gA = A  + (size_t)tm * GBM * K;
    const unsigned short* gB = Bt + (size_t)tn * GBN * K;

    const int NT = K >> 5;          // K-tiles of 32 (= 64 here, mult of 4)

    floatx4 acc[8][4] = {};
    short8 xa0[4], xa1[4], xb[4];   // fragment set X (even tiles)
    short8 ya0[4], ya1[4], yb[4];   // fragment set Y (odd tiles)

    // prologue: stage tiles 0,1,2 (12 loads); retire tile0 (keep 8 in flight)
    stage_op(gA, &lds[0][0],    0, K, tid);
    stage_op(gB, &lds[0][8192], 0, K, tid);
    stage_op(gA, &lds[1][0],    1, K, tid);
    stage_op(gB, &lds[1][8192], 1, K, tid);
    stage_op(gA, &lds[2][0],    2, K, tid);
    stage_op(gB, &lds[2][8192], 2, K, tid);
    asm volatile("s_waitcnt vmcnt(8)" ::: "memory");
    __builtin_amdgcn_s_barrier();

    for (unsigned t = 0; t < (unsigned)NT; t += 4) {
        // ---- u = 0: read tile t -> X, compute tile t-1 on Y ----
        {
            int ts = (int)t + 3; if (ts > NT - 1) ts = NT - 1;
            stage_op(gA, &lds[3][0],    ts, K, tid);
            stage_op(gB, &lds[3][8192], ts, K, tid);
            read_frags(&lds[0][0], &lds[0][8192], rowA0, rowB0, soff, xa0, xa1, xb);
            if (t > 0) mfma_tile(ya0, ya1, yb, acc);
            asm volatile("s_waitcnt vmcnt(8) lgkmcnt(0)" ::: "memory");
            __builtin_amdgcn_s_barrier();
        }
        // ---- u = 1: read tile t+1 -> Y, compute tile t on X ----
        {
            int ts = (int)t + 4; if (ts > NT - 1) ts = NT - 1;
            stage_op(gA, &lds[0][0],    ts, K, tid);
            stage_op(gB, &lds[0][8192], ts, K, tid);
            read_frags(&lds[1][0], &lds[1][8192], rowA0, rowB0, soff, ya0, ya1, yb);
            mfma_tile(xa0, xa1, xb, acc);
            asm volatile("s_waitcnt vmcnt(8) lgkmcnt(0)" ::: "memory");
            __builtin_amdgcn_s_barrier();
        }
        // ---- u = 2: read tile t+2 -> X, compute tile t+1 on Y ----
        {
            int ts = (int)t + 5; if (ts > NT - 1) ts = NT - 1;
            stage_op(gA, &lds[1][0],    ts, K, tid);
            stage_op(gB, &lds[1][8192], ts, K, tid);
            read_frags(&lds[2][0], &lds[2][8192], rowA0, rowB0, soff, xa0, xa1, xb);
            mfma_tile(ya0, ya1, yb, acc);
            asm volatile("s_waitcnt vmcnt(8) lgkmcnt(0)" ::: "memory");
            __builtin_amdgcn_s_barrier();
        }
        // ---- u = 3: read tile t+3 -> Y, compute tile t+2 on X ----
        {
            int ts = (int)t + 6; if (ts > NT - 1) ts = NT - 1;
            stage_op(gA, &lds[2][0],    ts, K, tid);
            stage_op(gB, &lds[2][8192], ts, K, tid);
            read_frags(&lds[3][0], &lds[3][8192], rowA0, rowB0, soff, ya0, ya1, yb);
            mfma_tile(xa0, xa1, xb, acc);
            asm volatile("s_waitcnt vmcnt(8) lgkmcnt(0)" ::: "memory");
            __builtin_amdgcn_s_barrier();
        }
    }
    // epilogue compute: tile NT-1 (odd -> set Y)
    mfma_tile(ya0, ya1, yb, acc);

    // epilogue: C/D layout col = lane&15 (N from B), row = quad*4 + reg (M)
    const size_t bm = (size_t)tm * GBM;
    const size_t bn = (size_t)tn * GBN;
    #pragma unroll
    for (int mi = 0; mi < 8; ++mi) {
        #pragma unroll
        for (int ni = 0; ni < 4; ++ni) {
            size_t col = bn + (size_t)waveN * 64 + ni * 16 + l16;
            #pragma unroll
            for (int r = 0; r < 4; ++r) {
                size_t row = bm + (size_t)waveM * 128 + mi * 16 + quad * 4 + r;
                C[row * N + col] = acc[mi][ni][r];
            }
        }
    }
}

// ---------------------------------------------------------------------------
extern "C" void kernel_launch(void* const* d_in, const int* in_sizes, int n_in,
                              void* d_out, int out_size, void* d_ws, size_t ws_size,
                              hipStream_t stream) {
    const float* x      = (const float*)d_in[0];
    const float* scale  = (const float*)d_in[1];
    const float* lnbias = (const float*)d_in[2];
    const float* W      = (const float*)d_in[3];

    const int H = in_sizes[1];                 // 2048
    const int M = in_sizes[0] / H;             // S*B = 8192
    const int F = in_sizes[3] / H;             // 8192

    float* z = (float*)d_out;                  // [M][F]
    float* y = z + (size_t)M * F;              // [M][H]

    unsigned short* Abf = (unsigned short*)d_ws;            // [M][H] bf16
    unsigned short* Btb = Abf + (size_t)M * H;              // [F][H] bf16

    ln_kernel<<<M, 256, 0, stream>>>(x, scale, lnbias, y, Abf, H);
    transpose_cast_kernel<<<dim3(F / 64, H / 64), 256, 0, stream>>>(W, Btb, H, F);
    gemm_bf16_8w<<<dim3((M / GBM) * (F / GBN)), 512, 0, stream>>>(Abf, Btb, z, M, F, H);
}

// Round 6
// 665.690 us; speedup vs baseline: 1.0295x; 1.0295x over previous
//
#include <hip/hip_runtime.h>
#include <stdint.h>

// ---------------------------------------------------------------------------
// LayerNormDenseGeneral: y = LN(x)*scale+bias; z = y @ W.  Outputs (z, y).
// Shapes: x[S,B,H]=[2048,4,2048] fp32, W[H,F]=[2048,8192] fp32.
// Round 8: two levers, schedule unchanged from r7 (4-ring, distance-3,
// vmcnt(8), reg X/Y dbuf, one barrier/tile):
//  (1) FETCH_SIZE anomaly fix: 540 MB fetched vs 64 MiB operand ideal ->
//      C writes (262 MB/dispatch) churn L3 and evict A/Bt panels. C, y
//      stores and x, W loads are now NON-TEMPORAL (single-use streams);
//      ybf/Btb stay cached (GEMM re-reads them from L3).
//  (2) MFMA shape 16x16x32 -> 32x32x16 (ceiling 2495 vs 2075 TF): MFMA
//      bill per K-tile 1216 -> ~1030 cyc. Same LDS traffic (12 b128/wave),
//      same acc budget. C/D layout col=lane&31, row=(reg&3)+8*(reg>>2)+
//      4*(lane>>5) [m74/m101-verified]; A/B frag k-octet = lane>>5.
// ws layout: [0, M*K*2) = A bf16 ; [M*K*2, M*K*2 + F*K*2) = Bt bf16. 64 MiB.
// ---------------------------------------------------------------------------

typedef __attribute__((ext_vector_type(8))) short short8;    // 8 x bf16 bits
typedef __attribute__((ext_vector_type(16))) float floatx16; // 32x32 MFMA acc
typedef __attribute__((ext_vector_type(4))) float f32x4;

__device__ __forceinline__ unsigned short f2bf(float f) {
    unsigned u = __builtin_bit_cast(unsigned, f);
    u += 0x7fffu + ((u >> 16) & 1u);   // round-to-nearest-even
    return (unsigned short)(u >> 16);
}

// ---------------- LayerNorm: one block per row, H=2048 ---------------------
__global__ __launch_bounds__(256) void ln_kernel(
    const float* __restrict__ x, const float* __restrict__ scale,
    const float* __restrict__ bias, float* __restrict__ y,
    unsigned short* __restrict__ ybf, int H)
{
    const int row = blockIdx.x;
    const float* xr = x + (size_t)row * H;
    const int tid = threadIdx.x;

    // H = 2048: each thread handles f32x4 at [tid] and [tid+256]
    f32x4 v0 = __builtin_nontemporal_load((const f32x4*)xr + tid);
    f32x4 v1 = __builtin_nontemporal_load((const f32x4*)xr + tid + 256);

    float s  = v0[0] + v0[1] + v0[2] + v0[3] + v1[0] + v1[1] + v1[2] + v1[3];
    float ss = v0[0]*v0[0] + v0[1]*v0[1] + v0[2]*v0[2] + v0[3]*v0[3]
             + v1[0]*v1[0] + v1[1]*v1[1] + v1[2]*v1[2] + v1[3]*v1[3];

    // wave(64) reduce
    #pragma unroll
    for (int off = 32; off > 0; off >>= 1) {
        s  += __shfl_down(s,  off, 64);
        ss += __shfl_down(ss, off, 64);
    }
    __shared__ float rs[4], rq[4];
    if ((tid & 63) == 0) { rs[tid >> 6] = s; rq[tid >> 6] = ss; }
    __syncthreads();
    float ts = rs[0] + rs[1] + rs[2] + rs[3];
    float tq = rq[0] + rq[1] + rq[2] + rq[3];
    float mean = ts / (float)H;
    float var  = tq / (float)H - mean * mean;
    float rstd = rsqrtf(var + 1e-6f);

    f32x4 sc0 = ((const f32x4*)scale)[tid];
    f32x4 sc1 = ((const f32x4*)scale)[tid + 256];
    f32x4 b0  = ((const f32x4*)bias)[tid];
    f32x4 b1  = ((const f32x4*)bias)[tid + 256];

    f32x4 o0 = (v0 - mean) * rstd * sc0 + b0;
    f32x4 o1 = (v1 - mean) * rstd * sc1 + b1;

    float* yr = y + (size_t)row * H;
    __builtin_nontemporal_store(o0, (f32x4*)yr + tid);
    __builtin_nontemporal_store(o1, (f32x4*)yr + tid + 256);

    unsigned short* br = ybf + (size_t)row * H;
    uint2 p0, p1;
    p0.x = (unsigned)f2bf(o0[0]) | ((unsigned)f2bf(o0[1]) << 16);
    p0.y = (unsigned)f2bf(o0[2]) | ((unsigned)f2bf(o0[3]) << 16);
    p1.x = (unsigned)f2bf(o1[0]) | ((unsigned)f2bf(o1[1]) << 16);
    p1.y = (unsigned)f2bf(o1[2]) | ((unsigned)f2bf(o1[3]) << 16);
    ((uint2*)br)[tid]       = p0;   // cached: re-read by GEMM
    ((uint2*)br)[tid + 256] = p1;
}

// -------- transpose-cast: W[K][F] fp32 -> Bt[F][K] bf16, 64x64 tiles -------
__global__ __launch_bounds__(256) void transpose_cast_kernel(
    const float* __restrict__ W, unsigned short* __restrict__ Bt,
    int K, int F)
{
    __shared__ float tile[64][65];
    const int kBase = blockIdx.y * 64;
    const int fBase = blockIdx.x * 64;
    const int tid = threadIdx.x;

    // read: 4 passes x (16 rows of 64 floats), coalesced nt f32x4
    #pragma unroll
    for (int p = 0; p < 4; ++p) {
        int kl = (tid >> 4) + p * 16;
        int fl = (tid & 15) * 4;
        f32x4 v = __builtin_nontemporal_load(
            (const f32x4*)&W[(size_t)(kBase + kl) * F + fBase + fl]);
        tile[kl][fl]     = v[0];
        tile[kl][fl + 1] = v[1];
        tile[kl][fl + 2] = v[2];
        tile[kl][fl + 3] = v[3];
    }
    __syncthreads();

    // write: 2 passes x (32 f-rows), each thread packs 8 bf16 = 16B store
    #pragma unroll
    for (int p = 0; p < 2; ++p) {
        int fl = (tid >> 3) + p * 32;
        int k8 = (tid & 7) * 8;
        unsigned w[4];
        #pragma unroll
        for (int j = 0; j < 4; ++j) {
            unsigned lo = f2bf(tile[k8 + 2*j][fl]);
            unsigned hi = f2bf(tile[k8 + 2*j + 1][fl]);
            w[j] = lo | (hi << 16);
        }
        uint4 out = make_uint4(w[0], w[1], w[2], w[3]);
        *(uint4*)&Bt[(size_t)(fBase + fl) * K + kBase + k8] = out;  // cached
    }
}

// ---------------- GEMM: C[M][N] = A[M][K] * Bt[N][K]^T (bf16 -> fp32) ------
// 256x256 tile, BK=32, 512 threads = 8 waves (2M x 4N), wave tile 128x64.
// LDS ring: 4 bufs x (A[256][32] @ 0 + B[256][32] @ 8192 shorts) = 128 KiB.
// Row = 64B = 4 chunks of 16B; phys slot s of row r holds logical chunk
// s ^ ((r>>1)&3) (conflict-free, measured 0). gload_lds dest linear;
// inverse XOR on the per-lane global source address.
//
// MFMA 32x32x16: wave tile = 4 rowblocks x 2 colblocks of 32x32, 2 k-steps
// of 16 per K-tile -> 16 MFMA/wave/K-tile. Lane l: row = base32 + (l&31),
// k-octet = l>>5 -> chunk(s) = 2s + (l>>5), phys slot = chunk ^ ((l31>>1)&3).
// Per-16-lane bank spread: 2-way max (free, m136).
//
// Pipeline (register fragment double-buffer, sets X/Y by tile parity):
//   body t: stage(t+3 clamped) -> buf[(t+3)&3]
//           ds_read 12 frags(t) from buf[t&3] -> set (t&1)
//           if (t>0) 16 MFMA on set ((t-1)&1)
//           s_waitcnt vmcnt(8) lgkmcnt(0); s_barrier
//   epilogue: 16 MFMA on set ((NT-1)&1); nontemporal C store.
#define GBM 256
#define GBN 256
#define GBK 32

__device__ __forceinline__ void gload16(const unsigned short* src,
                                        unsigned short* dst) {
    __builtin_amdgcn_global_load_lds(
        (const __attribute__((address_space(1))) unsigned int*)src,
        (__attribute__((address_space(3))) unsigned int*)dst, 16, 0, 0);
}

// stage one operand K-tile (256 rows x 32 k = 16KB) = 2 loads/thread
__device__ __forceinline__ void stage_op(
    const unsigned short* __restrict__ g, unsigned short* dst,
    int t, int K, int tid)
{
    #pragma unroll
    for (int i = 0; i < 2; ++i) {
        int e = i * 512 + tid;
        int r = e >> 2;                         // row 0..255
        int c = (e & 3) ^ ((r >> 1) & 3);       // inverse swizzle on source
        gload16(g + (size_t)r * K + t * GBK + c * 8, dst + e * 8);
    }
}

__device__ __forceinline__ void read_frags32(
    const unsigned short* bufA, const unsigned short* bufB,
    int rA, int rB, int s0a, int s1a,
    short8 (&a)[4][2], short8 (&b)[2][2])
{
    #pragma unroll
    for (int rb = 0; rb < 4; ++rb) {
        const unsigned short* rp = bufA + (rA + rb * 32) * 32;
        a[rb][0] = *(const short8*)(rp + s0a);
        a[rb][1] = *(const short8*)(rp + s1a);
    }
    #pragma unroll
    for (int cb = 0; cb < 2; ++cb) {
        const unsigned short* rp = bufB + (rB + cb * 32) * 32;
        b[cb][0] = *(const short8*)(rp + s0a);
        b[cb][1] = *(const short8*)(rp + s1a);
    }
}

__device__ __forceinline__ void mfma_tile32(
    const short8 (&a)[4][2], const short8 (&b)[2][2], floatx16 (&acc)[4][2])
{
    __builtin_amdgcn_s_setprio(1);
    #pragma unroll
    for (int rb = 0; rb < 4; ++rb)
        #pragma unroll
        for (int cb = 0; cb < 2; ++cb) {
            acc[rb][cb] = __builtin_amdgcn_mfma_f32_32x32x16_bf16(
                a[rb][0], b[cb][0], acc[rb][cb], 0, 0, 0);
            acc[rb][cb] = __builtin_amdgcn_mfma_f32_32x32x16_bf16(
                a[rb][1], b[cb][1], acc[rb][cb], 0, 0, 0);
        }
    __builtin_amdgcn_s_setprio(0);
}

__global__ __launch_bounds__(512, 2) void gemm_bf16_8w(
    const unsigned short* __restrict__ A,   // [M][K] bf16
    const unsigned short* __restrict__ Bt,  // [N][K] bf16
    float* __restrict__ C,                  // [M][N] fp32
    int M, int N, int K)
{
    __shared__ __align__(128) unsigned short lds[4][16384]; // 128 KiB ring

    const int tid   = threadIdx.x;
    const int lane  = tid & 63;
    const int wave  = tid >> 6;     // 0..7
    const int waveM = wave >> 2;    // 0..1
    const int waveN = wave & 3;     // 0..3
    const int l31   = lane & 31;
    const int lhi   = lane >> 5;    // k-octet
    const int xsw   = (l31 >> 1) & 3;            // row-XOR (lane-constant)
    const int s0a   = ((0 + lhi) ^ xsw) * 8;     // k-step 0 slot offset
    const int s1a   = ((2 + lhi) ^ xsw) * 8;     // k-step 1 slot offset
    const int rA    = waveM * 128 + l31;
    const int rB    = waveN * 64 + l31;

    // XCD-aware bijective swizzle (nwg = 1024, divisible by 8)
    const int nwg = gridDim.x;
    const int cpx = nwg >> 3;
    const int bid = blockIdx.x;
    const int wg  = (bid & 7) * cpx + (bid >> 3);
    const int tilesN = N >> 8;
    const int tm = wg / tilesN;
    const int tn = wg % tilesN;

    const unsigned short* gA = A  + (size_t)tm * GBM * K;
    const unsigned short* gB = Bt + (size_t)tn * GBN * K;

    const int NT = K >> 5;          // K-tiles of 32 (= 64 here, mult of 4)

    floatx16 acc[4][2] = {};
    short8 xa[4][2], xb[2][2];      // fragment set X (even tiles)
    short8 ya[4][2], yb[2][2];      // fragment set Y (odd tiles)

    // prologue: stage tiles 0,1,2 (12 loads); retire tile0 (keep 8 in flight)
    stage_op(gA, &lds[0][0],    0, K, tid);
    stage_op(gB, &lds[0][8192], 0, K, tid);
    stage_op(gA, &lds[1][0],    1, K, tid);
    stage_op(gB, &lds[1][8192], 1, K, tid);
    stage_op(gA, &lds[2][0],    2, K, tid);
    stage_op(gB, &lds[2][8192], 2, K, tid);
    asm volatile("s_waitcnt vmcnt(8)" ::: "memory");
    __builtin_amdgcn_s_barrier();

    for (unsigned t = 0; t < (unsigned)NT; t += 4) {
        // ---- u = 0: read tile t -> X, compute tile t-1 on Y ----
        {
            int ts = (int)t + 3; if (ts > NT - 1) ts = NT - 1;
            stage_op(gA, &lds[3][0],    ts, K, tid);
            stage_op(gB, &lds[3][8192], ts, K, tid);
            read_frags32(&lds[0][0], &lds[0][8192], rA, rB, s0a, s1a, xa, xb);
            if (t > 0) mfma_tile32(ya, yb, acc);
            asm volatile("s_waitcnt vmcnt(8) lgkmcnt(0)" ::: "memory");
            __builtin_amdgcn_s_barrier();
        }
        // ---- u = 1: read tile t+1 -> Y, compute tile t on X ----
        {
            int ts = (int)t + 4; if (ts > NT - 1) ts = NT - 1;
            stage_op(gA, &lds[0][0],    ts, K, tid);
            stage_op(gB, &lds[0][8192], ts, K, tid);
            read_frags32(&lds[1][0], &lds[1][8192], rA, rB, s0a, s1a, ya, yb);
            mfma_tile32(xa, xb, acc);
            asm volatile("s_waitcnt vmcnt(8) lgkmcnt(0)" ::: "memory");
            __builtin_amdgcn_s_barrier();
        }
        // ---- u = 2: read tile t+2 -> X, compute tile t+1 on Y ----
        {
            int ts = (int)t + 5; if (ts > NT - 1) ts = NT - 1;
            stage_op(gA, &lds[1][0],    ts, K, tid);
            stage_op(gB, &lds[1][8192], ts, K, tid);
            read_frags32(&lds[2][0], &lds[2][8192], rA, rB, s0a, s1a, xa, xb);
            mfma_tile32(ya, yb, acc);
            asm volatile("s_waitcnt vmcnt(8) lgkmcnt(0)" ::: "memory");
            __builtin_amdgcn_s_barrier();
        }
        // ---- u = 3: read tile t+3 -> Y, compute tile t+2 on X ----
        {
            int ts = (int)t + 6; if (ts > NT - 1) ts = NT - 1;
            stage_op(gA, &lds[2][0],    ts, K, tid);
            stage_op(gB, &lds[2][8192], ts, K, tid);
            read_frags32(&lds[3][0], &lds[3][8192], rA, rB, s0a, s1a, ya, yb);
            mfma_tile32(xa, xb, acc);
            asm volatile("s_waitcnt vmcnt(8) lgkmcnt(0)" ::: "memory");
            __builtin_amdgcn_s_barrier();
        }
    }
    // epilogue compute: tile NT-1 (odd -> set Y)
    mfma_tile32(ya, yb, acc);

    // epilogue: C/D layout (32x32, m74/m101-verified):
    // col = lane&31, row = (reg&3) + 8*(reg>>2) + 4*(lane>>5)
    const size_t bm = (size_t)tm * GBM;
    const size_t bn = (size_t)tn * GBN;
    #pragma unroll
    for (int rb = 0; rb < 4; ++rb) {
        #pragma unroll
        for (int cb = 0; cb < 2; ++cb) {
            size_t col = bn + (size_t)waveN * 64 + cb * 32 + l31;
            #pragma unroll
            for (int i = 0; i < 16; ++i) {
                size_t row = bm + (size_t)waveM * 128 + rb * 32
                           + (i & 3) + 8 * (i >> 2) + 4 * lhi;
                __builtin_nontemporal_store(acc[rb][cb][i], &C[row * N + col]);
            }
        }
    }
}

// ---------------------------------------------------------------------------
extern "C" void kernel_launch(void* const* d_in, const int* in_sizes, int n_in,
                              void* d_out, int out_size, void* d_ws, size_t ws_size,
                              hipStream_t stream) {
    const float* x      = (const float*)d_in[0];
    const float* scale  = (const float*)d_in[1];
    const float* lnbias = (const float*)d_in[2];
    const float* W      = (const float*)d_in[3];

    const int H = in_sizes[1];                 // 2048
    const int M = in_sizes[0] / H;             // S*B = 8192
    const int F = in_sizes[3] / H;             // 8192

    float* z = (float*)d_out;                  // [M][F]
    float* y = z + (size_t)M * F;              // [M][H]

    unsigned short* Abf = (unsigned short*)d_ws;            // [M][H] bf16
    unsigned short* Btb = Abf + (size_t)M * H;              // [F][H] bf16

    ln_kernel<<<M, 256, 0, stream>>>(x, scale, lnbias, y, Abf, H);
    transpose_cast_kernel<<<dim3(F / 64, H / 64), 256, 0, stream>>>(W, Btb, H, F);
    gemm_bf16_8w<<<dim3((M / GBM) * (F / GBN)), 512, 0, stream>>>(Abf, Btb, z, M, F, H);
}